// Round 7
// baseline (247.575 us; speedup 1.0000x reference)
//
#include <hip/hip_runtime.h>

// DualModel3 R12: R11 body + 4.1 independent barrier-groups/CU + half the
// barriers.
// R11 post-mortem: 84us (best), but per-iter wall ~6300cyc vs ~500cyc
// critical path; MfmaUtil 8.1% == the kernel's intrinsic 6.8us of MFMA work.
// Residual invariant: 32 per-K-tile block-barrier convergences with only
// 544/256 = 2.1 independent blocks/CU to overlap them. R9 had more blocks
// but the old serialized body; R11 fixed the body at 2.1 blocks/CU.
// R12 changes only execution shape, keeping R11's verified machinery
// (frag-major A image + pack_a byte-identical, bslot swizzle, lgkm-only
// barriers, fc math):
//  - dec blocks BM=128 (pure addressing change: wave reads A-image mchunk
//    rg*4+w) -> 1024 dec + 32 fc = 1056 blocks = 4.1 groups/CU. XCD swizzle
//    keeps rg-siblings on one XCD -> duplicated W1 slab read is L2-served.
//  - superstage: B staged 2 k-tiles per barrier (16 barriers, not 32);
//    B regs loaded 2 superstages (=4 k-tiles) ahead.
//  - per-wave/iter: 4 A-frag loads + 4 ds_read + 4 MFMA (dec); acc 1x f32x16.
//    launch_bounds(256,4): cap 128, est ~95-110 VGPR, no spill.

typedef __bf16 bf16_t;
typedef __bf16 bf16x2v __attribute__((ext_vector_type(2)));
typedef __bf16 bf16x8 __attribute__((ext_vector_type(8)));
typedef float  f32x4  __attribute__((ext_vector_type(4)));
typedef float  f32x16 __attribute__((ext_vector_type(16)));

#define WS_REP_BYTES (1 << 20)     // 1 MB per A replica, 4 replicas

__device__ __forceinline__ int bslot(int n, int g) {
    return g ^ (n & 7) ^ (((n >> 3) & 3) << 1);
}

#define BARRIER() do { \
    asm volatile("s_waitcnt lgkmcnt(0)" ::: "memory"); \
    __builtin_amdgcn_s_barrier(); \
    asm volatile("" ::: "memory"); } while (0)

// ---------------------------------------------------------------- pass 1 ----
// (byte-identical to R11 — verified) Frag-major A image:
// byte = rep*1MB + kt*32768 + (mchunk*256 + g*32 + lane31)*16;
// slot holds x[mchunk*32 + l][kt*64 + g*8 .. +7] as bf16x8.
__global__ __launch_bounds__(256)
void pack_a(const float* __restrict__ x, char* __restrict__ ws)
{
    const int kt  = blockIdx.x & 31;
    const int rep = blockIdx.x >> 5;                  // 0..3
    char* dst = ws + (size_t)rep * WS_REP_BYTES + (size_t)kt * 32768;
    const int tid = threadIdx.x;
    #pragma unroll
    for (int ii = 0; ii < 8; ++ii) {
        const int gi  = tid + 256 * ii;               // 0..2047
        const int mr5 = gi >> 8, g = (gi >> 5) & 7, l = gi & 31;
        const float* sp = x + (size_t)(mr5 * 32 + l) * 2048 + kt * 64 + g * 8;
        f32x4 v0 = *(const f32x4*)sp, v1 = *(const f32x4*)(sp + 4);
        bf16x8 o;
        #pragma unroll
        for (int c = 0; c < 4; ++c) { o[c] = (bf16_t)v0[c]; o[4 + c] = (bf16_t)v1[c]; }
        *(bf16x8*)(dst + gi * 16) = o;
    }
}

// ---------------------------------------------------------------- pass 2 ----
__global__ __launch_bounds__(256, 4)    // cap 128 VGPR; 16KB LDS
void fused_dual(const char* __restrict__ ws,
                const float* __restrict__ W1,   // [4096,2048,4] fp32
                const float* __restrict__ fcW,  // [1000,2048] fp32
                const float* __restrict__ fcb,
                const float* __restrict__ b1,
                const float* __restrict__ W2,
                const float* __restrict__ b2,
                float* __restrict__ out)        // x1[256*1000] ++ x2[256*4096]
{
    __shared__ __align__(16) char lds[2][8192];   // B superstage dbuf (2kt/half)

    const int tid  = threadIdx.x;
    const int lane = tid & 63, w = tid >> 6;      // 4 waves
    const int l31  = lane & 31, half = lane >> 5;

    // XCD swizzle: 1056 = 8 x 132, bijective. dec rg-siblings adjacent.
    const int idx = blockIdx.x;
    const int wid = (idx & 7) * 132 + (idx >> 3);
    const bool is_fc = (wid >= 1024);
    const int d8 = wid >> 1, rg = wid & 1;        // dec: o in [d8*8, +8), m0=rg*128
    const int fcI = wid - 1024;                   // fc: cols [fcI*32, +32)

    const char* aRep = ws + (size_t)((idx & 7) >> 1) * WS_REP_BYTES;

    // B-frag read offsets (R11-verified swizzle)
    int bro[4];
    #pragma unroll
    for (int ks = 0; ks < 4; ++ks)
        bro[ks] = l31 * 128 + bslot(l31, ks * 2 + half) * 16;

    if (!is_fc) {
        // =================== decoder path: BM=128, BN=32 ===================
        const int aoff = (rg * 4 + w) * 4096 + half * 512 + l31 * 16;
        // staging map (R11-verified): o=(t>>5)&7, kg=(t>>2)&7, kp=t&3
        const int o = (tid >> 5) & 7, kg = (tid >> 2) & 7, kp = tid & 3;
        const float* bSrc = W1 + (size_t)(d8 * 8 + o) * 8192 + (kg * 8 + kp * 2) * 4;
        int dwo[4];
        #pragma unroll
        for (int h = 0; h < 4; ++h) {
            const int n = 4 * o + h;
            dwo[h] = n * 128 + bslot(n, kg) * 16 + kp * 4;
        }

        f32x16 acc;
        #pragma unroll
        for (int r = 0; r < 16; ++r) acc[r] = 0.f;

        bf16x8 aF0[4], aF1[4];
        f32x4  bRa[4], bRb[4];

        auto B_LOAD = [&](int ss, f32x4* R) {          // superstage = kt {2ss,2ss+1}
            const float* p = bSrc + (size_t)ss * 512;
            R[0] = *(const f32x4*)p;       R[1] = *(const f32x4*)(p + 4);
            R[2] = *(const f32x4*)(p+256); R[3] = *(const f32x4*)(p + 260);
        };
        auto B_WRITE = [&](const f32x4* R, char* lB) {
            #pragma unroll
            for (int ktl = 0; ktl < 2; ++ktl)
                #pragma unroll
                for (int h = 0; h < 4; ++h) {
                    bf16x2v v;
                    v[0] = (bf16_t)R[ktl * 2][h];
                    v[1] = (bf16_t)R[ktl * 2 + 1][h];
                    *(bf16x2v*)(lB + ktl * 4096 + dwo[h]) = v;
                }
        };
        auto A_PF = [&](int kt, bf16x8* F) {
            const char* ap = aRep + (size_t)kt * 32768 + aoff;
            #pragma unroll
            for (int ks = 0; ks < 4; ++ks)
                F[ks] = *(const bf16x8*)(ap + ks * 1024);
        };
        auto MM = [&](const bf16x8* F, const char* lB, int ktl) {
            #pragma unroll
            for (int ks = 0; ks < 4; ++ks) {
                bf16x8 bf = *(const bf16x8*)(lB + ktl * 4096 + bro[ks]);
                acc = __builtin_amdgcn_mfma_f32_32x32x16_bf16(F[ks], bf, acc, 0, 0, 0);
            }
        };

        B_LOAD(0, bRa); B_LOAD(1, bRb);
        A_PF(0, aF0);
        B_WRITE(bRa, lds[0]);
        BARRIER();

        #pragma unroll 1
        for (int ss2 = 0; ss2 < 8; ++ss2) {
            const int ss = ss2 * 2;
            {   // superstage ss (even, p=0): kts 2ss, 2ss+1
                int sl = ss + 2; if (sl > 15) sl = 15;
                B_LOAD(sl, bRa);
                A_PF(2 * ss + 1, aF1);
                MM(aF0, lds[0], 0);
                int ka = 2 * ss + 2; if (ka > 31) ka = 31;
                A_PF(ka, aF0);
                MM(aF1, lds[0], 1);
                B_WRITE(bRb, lds[1]);
                BARRIER();
            }
            {   // superstage ss+1 (odd, p=1): kts 2ss+2, 2ss+3
                int sl = ss + 3; if (sl > 15) sl = 15;
                B_LOAD(sl, bRb);
                int ka = 2 * ss + 3; if (ka > 31) ka = 31;
                A_PF(ka, aF1);
                MM(aF0, lds[1], 0);
                int kb = 2 * ss + 4; if (kb > 31) kb = 31;
                A_PF(kb, aF0);
                MM(aF1, lds[1], 1);
                B_WRITE(bRa, lds[0]);
                BARRIER();
            }
        }

        // epilogue: C/D col=lane&31(=n), row=(r&3)+8*(r>>2)+4*half (m-local)
        float* x2 = out + 256 * 1000;
        const int n_glob = d8 * 32 + l31;
        const float b1v = b1[n_glob], w2v = W2[n_glob];
        const float b2v = b2[n_glob >> 2];
        float* xs = (float*)lds;                      // [128 rows][8 o] = 4KB
        const int o8 = l31 >> 2;
        #pragma unroll
        for (int r = 0; r < 16; ++r) {
            float h = acc[r] + b1v;
            h = (h >= 0.f) ? h : 0.1f * h;            // leaky relu
            float wv = h * w2v;
            wv += __shfl_xor(wv, 1, 64);              // decoder's 4 h-cols
            wv += __shfl_xor(wv, 2, 64);
            if ((lane & 3) == 0) {
                const int row = w * 32 + (r & 3) + 8 * (r >> 2) + 4 * half;
                xs[row * 8 + o8] = wv + b2v;
            }
        }
        __syncthreads();
        {
            const int row = tid >> 1, part = tid & 1;
            f32x4 v = *(const f32x4*)(xs + row * 8 + part * 4);
            *(f32x4*)(x2 + (size_t)(rg * 128 + row) * 4096 + d8 * 8 + part * 4) = v;
        }
    } else {
        // =================== fc path: BM=256, BN=32 (R11 math) =============
        const int aoff = w * 8192 + half * 512 + l31 * 16;
        const int n = tid >> 3, kg = tid & 7;
        int c = fcI * 32 + n; if (c > 999) c = 999;   // stores guarded
        const float* bSrc = fcW + (size_t)c * 2048 + kg * 8;
        const int fcWoff = n * 128 + bslot(n, kg) * 16;

        f32x16 acc[2];
        #pragma unroll
        for (int i = 0; i < 2; ++i)
            #pragma unroll
            for (int r = 0; r < 16; ++r) acc[i][r] = 0.f;

        bf16x8 aF[8];
        f32x4  bRa[4], bRb[4];

        auto B_LOAD = [&](int ss, f32x4* R) {
            const float* p = bSrc + (size_t)ss * 128;
            R[0] = *(const f32x4*)p;        R[1] = *(const f32x4*)(p + 4);
            R[2] = *(const f32x4*)(p + 64); R[3] = *(const f32x4*)(p + 68);
        };
        auto B_WRITE = [&](const f32x4* R, char* lB) {
            #pragma unroll
            for (int ktl = 0; ktl < 2; ++ktl) {
                bf16x8 v;
                #pragma unroll
                for (int j = 0; j < 4; ++j) {
                    v[j]     = (bf16_t)R[ktl * 2][j];
                    v[4 + j] = (bf16_t)R[ktl * 2 + 1][j];
                }
                *(bf16x8*)(lB + ktl * 4096 + fcWoff) = v;
            }
        };
        auto A_PF = [&](int kt) {
            const char* ap = aRep + (size_t)kt * 32768 + aoff;
            #pragma unroll
            for (int i = 0; i < 2; ++i)
                #pragma unroll
                for (int ks = 0; ks < 4; ++ks)
                    aF[i * 4 + ks] = *(const bf16x8*)(ap + i * 4096 + ks * 1024);
        };
        auto MM = [&](const char* lB, int ktl) {
            #pragma unroll
            for (int ks = 0; ks < 4; ++ks) {
                bf16x8 bf = *(const bf16x8*)(lB + ktl * 4096 + bro[ks]);
                #pragma unroll
                for (int i = 0; i < 2; ++i)
                    acc[i] = __builtin_amdgcn_mfma_f32_32x32x16_bf16(aF[i * 4 + ks], bf, acc[i], 0, 0, 0);
            }
        };

        B_LOAD(0, bRa); B_LOAD(1, bRb);
        B_WRITE(bRa, lds[0]);
        BARRIER();

        #pragma unroll 1
        for (int ss2 = 0; ss2 < 8; ++ss2) {
            const int ss = ss2 * 2;
            {
                int sl = ss + 2; if (sl > 15) sl = 15;
                B_LOAD(sl, bRa);
                A_PF(2 * ss);     MM(lds[0], 0);
                A_PF(2 * ss + 1); MM(lds[0], 1);
                B_WRITE(bRb, lds[1]);
                BARRIER();
            }
            {
                int sl = ss + 3; if (sl > 15) sl = 15;
                B_LOAD(sl, bRb);
                A_PF(2 * ss + 2); MM(lds[1], 0);
                A_PF(2 * ss + 3); MM(lds[1], 1);
                B_WRITE(bRa, lds[0]);
                BARRIER();
            }
        }

        const int cc = fcI * 32 + l31;
        if (cc < 1000) {
            const float bias = fcb[cc];
            #pragma unroll
            for (int i = 0; i < 2; ++i)
            #pragma unroll
            for (int r = 0; r < 16; ++r) {
                const int m = w * 64 + i * 32 + (r & 3) + 8 * (r >> 2) + 4 * half;
                out[m * 1000 + cc] = acc[i][r] + bias;
            }
        }
    }
}

extern "C" void kernel_launch(void* const* d_in, const int* in_sizes, int n_in,
                              void* d_out, int out_size, void* d_ws, size_t ws_size,
                              hipStream_t stream)
{
    (void)in_sizes; (void)n_in; (void)out_size; (void)ws_size;
    const float* x   = (const float*)d_in[0];
    const float* fcW = (const float*)d_in[1];
    const float* fcb = (const float*)d_in[2];
    const float* W1  = (const float*)d_in[3];
    const float* b1  = (const float*)d_in[4];
    const float* W2  = (const float*)d_in[5];
    const float* b2  = (const float*)d_in[6];
    char* ws = (char*)d_ws;                       // 4 MB (< proven-safe 5 MB)
    pack_a<<<128, 256, 0, stream>>>(x, ws);
    fused_dual<<<1056, 256, 0, stream>>>(ws, W1, fcW, fcb, b1, W2, b2, (float*)d_out);
}